// Round 10
// baseline (228.142 us; speedup 1.0000x reference)
//
#include <hip/hip_runtime.h>
#include <math.h>

#define NSD 9
#define NPD 2
#define NAD 7
#define NH  256
#define NIN 16   // NSD + NAD
#define LOSCALE 2048.0f
#define LOINV   (1.0f / 2048.0f)
#define NPACKB 152

typedef _Float16 half8 __attribute__((ext_vector_type(8)));
typedef float    floatx4 __attribute__((ext_vector_type(4)));

// ---------------------------------------------------------------------------
// Swapped-operand register-resident design.
// R9 post-mortem: spill-free at 138 us; LDS READ BW is the binding pipe
// (every wave reads the full 36 KB slice per kc: 16 waves/CU x 4h x 8kc x
// 36 KB ~ 18.4 MB/CU ~ 100 us at 85 B/cyc > 59 us MFMA floor).
// R10 (pair-split): waves pair up (0,1) and (2,3). Each wave computes its
// HALF of the t-range (8 tiles) for BOTH row groups in the pair: per-kc
// reads drop 36 -> 20 KB (-44%); MFMA +10.5% (L1 done per group instead of
// exchanging h1). Partner's inp B-frag is built from the shared inpL.
// L3 partial sums exchanged once per step through the DEAD staging buffer
// sb[1] (always holds slice 7 at the epilogue; cur is 0 there since it
// flips 8x per step). Accumulators stay 8t x 2g x (C1+C2) = 128 AGPR.
// Runtime-uniform group picks use ternaries, never runtime array indices
// (rule #20). Math identical except L3 sum re-association (ulp-level).
//
// Frag algebra (verified R4): C/D layout lane->(D[slot=(l>>4)*4+r][col=l&15]);
// A-frag lane->(A[row=l&15][k=(l>>4)*8+j]); B-frag lane->(B[k=(l>>4)*8+j][n=l&15]).
// Weight cols permuted by colmap(t,s)=32(t>>1)+8(s>>2)+4(t&1)+(s&3) so
// layer-t output slots land on the next layer's B-frag k-indices:
// kc = t>>1, j = 4(t&1)+r. Bias b1 folds via K=16->32 pad (inp[16]=1.0).
//
// pc layout, slice kc (18432 fp16 units = 36 KB):
//   units     0..16383 : w2 frags, t*1024 + (hi 0..511 | lo 512..1023)
//   units 16384..18431 : p1 frags, tt*1024 + (hi | lo), t = kc*2 + tt
// ---------------------------------------------------------------------------

__device__ __forceinline__ void stage16(const _Float16* g, _Float16* l)
{
    __builtin_amdgcn_global_load_lds(
        (const __attribute__((address_space(1))) void*)g,
        (__attribute__((address_space(3))) void*)l, 16, 0, 0);
}

// ---------------------------------------------------------------------------
// Fused prep kernel: blocks 0..151 pack weights (64 active threads);
// blocks 152.. run the action-proposal (unchanged, verified). Fusing saves
// one launch + serialization of two tiny kernels.
// ---------------------------------------------------------------------------
__global__ __launch_bounds__(256) void k_prep(
    const float* __restrict__ w1, const float* __restrict__ b1,
    const float* __restrict__ w2, const float* __restrict__ w3,
    _Float16* __restrict__ pc, _Float16* __restrict__ p3,
    const float* __restrict__ state, const float* __restrict__ proprio,
    const float* __restrict__ noise, const float* __restrict__ pw1,
    const float* __restrict__ pb1, const float* __restrict__ pw2,
    const float* __restrict__ pb2, float* __restrict__ cand, int B)
{
    const int bid = blockIdx.x;
    if (bid < NPACKB) {
        if (threadIdx.x >= 64) return;
        const int lane = threadIdx.x;
        const int q = lane >> 4, ln = lane & 15;
        half8 hv, lv;
        _Float16* dst;
        if (bid < 16) {
            // L1: A = [w1 ; b1 ; 0]^T, colmap'd cols, k in [0,32).
            const int t = bid;
            const int c = 32*(t>>1) + 8*(ln>>2) + 4*(t&1) + (ln&3);
#pragma unroll
            for (int j = 0; j < 8; ++j) {
                const int k = 8*q + j;
                const float x = (k < NIN) ? w1[k*NH + c]
                                          : (k == NIN ? b1[c] : 0.0f);
                const _Float16 h = (_Float16)x;
                hv[j] = h; lv[j] = (_Float16)((x - (float)h) * LOSCALE);
            }
            dst = pc + (size_t)(t >> 1) * 18432 + 16384 + (size_t)(t & 1) * 1024;
        } else if (bid < 144) {
            // L2: A = w2^T, colmap'd cols, natural k.
            const int idx = bid - 16, t = idx >> 3, kc = idx & 7;
            const int c = 32*(t>>1) + 8*(ln>>2) + 4*(t&1) + (ln&3);
#pragma unroll
            for (int j = 0; j < 8; ++j) {
                const int k = kc*32 + 8*q + j;
                const float x = w2[k*NH + c];
                const _Float16 h = (_Float16)x;
                hv[j] = h; lv[j] = (_Float16)((x - (float)h) * LOSCALE);
            }
            dst = pc + (size_t)kc * 18432 + (size_t)t * 1024;
        } else {
            // L3: A = w3^T [9->16 pad rows], natural slots.
            const int kc = bid - 144;
#pragma unroll
            for (int j = 0; j < 8; ++j) {
                const int k = kc*32 + 8*q + j;
                const float x = (ln < NSD) ? w3[k*NSD + ln] : 0.0f;
                const _Float16 h = (_Float16)x;
                hv[j] = h; lv[j] = (_Float16)((x - (float)h) * LOSCALE);
            }
            dst = p3 + (size_t)kc * 1024;
        }
        *(half8*)&dst[lane*8]       = hv;
        *(half8*)&dst[512 + lane*8] = lv;
        return;
    }

    // ---- proposal part (unchanged math) ----
    const int pbid = bid - NPACKB;
    const int wave = threadIdx.x >> 6;
    const int lane = threadIdx.x & 63;
    const int b = pbid * 4 + wave;
    if (b >= B) return;

    float x[11];
#pragma unroll
    for (int k = 0; k < 9; ++k) x[k] = state[b * NSD + k];
    x[9]  = proprio[b * NPD + 0];
    x[10] = proprio[b * NPD + 1];

    float hc[4];
#pragma unroll
    for (int i = 0; i < 4; ++i) {
        const int c = lane + 64 * i;
        float acc = pb1[c];
#pragma unroll
        for (int k = 0; k < 11; ++k) acc = fmaf(x[k], pw1[k * NH + c], acc);
        hc[i] = fmaxf(acc, 0.0f);
    }

    float base[7];
#pragma unroll
    for (int j = 0; j < 7; ++j) {
        float p = 0.0f;
#pragma unroll
        for (int i = 0; i < 4; ++i)
            p = fmaf(hc[i], pw2[(lane + 64 * i) * NAD + j], p);
#pragma unroll
        for (int off = 32; off >= 1; off >>= 1) p += __shfl_xor(p, off, 64);
        base[j] = tanhf(p + pb2[j]);
    }

    if (lane < 8 * NAD) {
        const int s = lane / NAD, j = lane % NAD;
        float bj = base[0];
#pragma unroll
        for (int jj = 1; jj < 7; ++jj) if (j == jj) bj = base[jj];
        float v = bj + 0.2f * noise[((size_t)s * B + b) * NAD + j];
        v = fminf(fmaxf(v, -1.0f), 1.0f);
        cand[((size_t)s * B + b) * NAD + j] = v;
    }
}

// ---------------------------------------------------------------------------
// Kernel 2: rollout, pair-split. 256 threads = 4 waves = 2 pairs; each wave
// owns 16 (s,b) rows AND computes its 8-tile t-half for both rows groups of
// its pair. Per-kc LDS reads: 20 KB/wave (vs 36 unsplit).
// LDS: 72 KB stage (sb[1] doubles as the epilogue exchange buffer) +
// 5 KB inpL + 1 KB b2L ~= 78 KB -> 2 blocks/CU (register-capped anyway).
// ---------------------------------------------------------------------------
__global__ __launch_bounds__(256, 2) void k_rollout(
    const float* __restrict__ state, const float* __restrict__ target,
    const float* __restrict__ cand,
    const _Float16* __restrict__ pc, const _Float16* __restrict__ p3,
    const float* __restrict__ b2, const float* __restrict__ b3,
    const int* __restrict__ hor_ptr, float* __restrict__ cost, int B)
{
    __shared__ _Float16 sb[2][18432];   // slice layout == pc slice layout
    __shared__ float inpL[4][16][20];
    __shared__ float b2L[NH];

    const int tid  = threadIdx.x;
    const int wv   = tid >> 6;
    const int lane = tid & 63;
    const int q = lane >> 4, ln = lane & 15;
    const int wpair = wv & 2;           // first wave of this pair
    const int gown  = wv & 1;           // own rows = group (wv&1) in pair
    const int tbase = gown * 8;         // this wave's t-half
    const int chunk = blockIdx.x * 4 + wv;
    const int p0 = chunk * 16;
    const int s  = p0 / B;
    const int b0 = p0 % B;
    const int horizon = *hor_ptr;

    // Stage slice kc: 9 rounds x 256 thr x 16 B, contiguous global src.
    auto STAGE = [&](int buf, int kc) {
        const _Float16* gbase = pc + (size_t)kc * 18432 + tid * 8;
        _Float16* lbase = &sb[buf][wv * 512];
#pragma unroll
        for (int i = 0; i < 9; ++i)
            stage16(gbase + i * 2048, lbase + i * 2048);
    };

    b2L[tid] = b2[tid];
    if (q == 0) {
        float* row = &inpL[wv][ln][0];
        const int b = b0 + ln;
#pragma unroll
        for (int k = 0; k < NSD; ++k) row[k] = state[b * NSD + k];
#pragma unroll
        for (int j = 0; j < NAD; ++j)
            row[NSD + j] = cand[((size_t)s * B + b) * NAD + j];
        row[16] = 1.0f; row[17] = 0.0f; row[18] = 0.0f; row[19] = 0.0f;
    }
    float tg[3] = {0.0f, 0.0f, 0.0f};
    if (q == 0) {
#pragma unroll
        for (int r = 0; r < 3; ++r) tg[r] = target[(b0 + ln) * 3 + r];
    }
    float b3v[4];
#pragma unroll
    for (int r = 0; r < 4; ++r) {
        const int f = q * 4 + r;
        b3v[r] = (f < NSD) ? b3[f] : 0.0f;
    }
    float costAcc = 0.0f;

    STAGE(0, 0);                                      // prologue: slice 0
    asm volatile("s_waitcnt vmcnt(0)" ::: "memory");
    __syncthreads();   // b2L + initial inpL (cross-wave) + staged slice 0
    int cur = 0;

    const floatx4 z4 = {0.0f, 0.0f, 0.0f, 0.0f};

    for (int h = 0; h < horizon; ++h) {
        // ---- inp B-frags for BOTH row groups of the pair (from inpL) ----
        half8 bh[2], bl[2];
#pragma unroll
        for (int g = 0; g < 2; ++g) {
            const float* row = &inpL[wpair + g][ln][0];
            float4 fa = {0, 0, 0, 0}, fb = {0, 0, 0, 0};
            if (q < 3) fa = *(const float4*)&row[8 * q];
            if (q < 2) fb = *(const float4*)&row[8 * q + 4];
            const float vv[8] = {fa.x, fa.y, fa.z, fa.w, fb.x, fb.y, fb.z, fb.w};
#pragma unroll
            for (int j = 0; j < 8; ++j) {
                const _Float16 hh = (_Float16)vv[j];
                bh[g][j] = hh;
                bl[g][j] = (_Float16)((vv[j] - (float)hh) * LOSCALE);
            }
        }

        // ---- acc banks: 8 t-tiles x 2 groups (128 AGPR) ----
        floatx4 C1[8][2], C2[8][2];
#pragma unroll
        for (int tt = 0; tt < 8; ++tt)
#pragma unroll
            for (int g = 0; g < 2; ++g) { C1[tt][g] = z4; C2[tt][g] = z4; }

        // ---- kc loop: stage next; L1 (both groups) + half-t-loop from LDS --
        for (int kc = 0; kc < 8; ++kc) {
            const int nkc = (kc < 7) ? kc + 1 : 0;    // kc=7 restages slice 0
            STAGE(cur ^ 1, nkc);

            const half8 a1h0 = *(const half8*)&sb[cur][16384 + lane*8];
            const half8 a1l0 = *(const half8*)&sb[cur][16384 + 512 + lane*8];
            const half8 a1h1 = *(const half8*)&sb[cur][16384 + 1024 + lane*8];
            const half8 a1l1 = *(const half8*)&sb[cur][16384 + 1536 + lane*8];
            half8 h1h[2], h1l[2];
#pragma unroll
            for (int g = 0; g < 2; ++g) {
                floatx4 c1t = __builtin_amdgcn_mfma_f32_16x16x32_f16(a1h0, bh[g], z4, 0, 0, 0);
                floatx4 c2t = __builtin_amdgcn_mfma_f32_16x16x32_f16(a1h0, bl[g], z4, 0, 0, 0);
                c2t = __builtin_amdgcn_mfma_f32_16x16x32_f16(a1l0, bh[g], c2t, 0, 0, 0);
#pragma unroll
                for (int r = 0; r < 4; ++r) {
                    const float v = fmaxf(fmaf(c2t[r], LOINV, c1t[r]), 0.0f);
                    const _Float16 hh = (_Float16)v;
                    h1h[g][r] = hh;
                    h1l[g][r] = (_Float16)((v - (float)hh) * LOSCALE);
                }
                c1t = __builtin_amdgcn_mfma_f32_16x16x32_f16(a1h1, bh[g], z4, 0, 0, 0);
                c2t = __builtin_amdgcn_mfma_f32_16x16x32_f16(a1h1, bl[g], z4, 0, 0, 0);
                c2t = __builtin_amdgcn_mfma_f32_16x16x32_f16(a1l1, bh[g], c2t, 0, 0, 0);
#pragma unroll
                for (int r = 0; r < 4; ++r) {
                    const float v = fmaxf(fmaf(c2t[r], LOINV, c1t[r]), 0.0f);
                    const _Float16 hh = (_Float16)v;
                    h1h[g][4 + r] = hh;
                    h1l[g][4 + r] = (_Float16)((v - (float)hh) * LOSCALE);
                }
            }

            // half t-loop: 8 t x {2 ds_read + 6 MFMA (both groups)}.
#pragma unroll
            for (int tt = 0; tt < 8; ++tt) {
                const int t = tbase + tt;
                const half8 a2h = *(const half8*)&sb[cur][t * 1024 + lane * 8];
                const half8 a2l = *(const half8*)&sb[cur][t * 1024 + 512 + lane * 8];
#pragma unroll
                for (int g = 0; g < 2; ++g) {
                    C1[tt][g] = __builtin_amdgcn_mfma_f32_16x16x32_f16(a2h, h1h[g], C1[tt][g], 0, 0, 0);
                    C2[tt][g] = __builtin_amdgcn_mfma_f32_16x16x32_f16(a2h, h1l[g], C2[tt][g], 0, 0, 0);
                    C2[tt][g] = __builtin_amdgcn_mfma_f32_16x16x32_f16(a2l, h1h[g], C2[tt][g], 0, 0, 0);
                }
            }

            __syncthreads();   // implicit vmcnt(0): stage landed during compute
            cur ^= 1;          // cur returns to 0 after 8 flips
        }

        // ---- epilogue: finish h2 per (t, g); partial L3 over own kc2 half --
        floatx4 D1[2] = {z4, z4}, D2[2] = {z4, z4};
        half8 h2h[2], h2l[2];
#pragma unroll
        for (int tt = 0; tt < 8; ++tt) {
            const int t = tbase + tt;
            const float4 bb = *(const float4*)&b2L[32*(t>>1) + 8*q + 4*(t&1)];
            const float bbv[4] = {bb.x, bb.y, bb.z, bb.w};
#pragma unroll
            for (int g = 0; g < 2; ++g)
#pragma unroll
                for (int r = 0; r < 4; ++r) {
                    const float v = fmaxf(C1[tt][g][r] + LOINV * C2[tt][g][r] + bbv[r], 0.0f);
                    const _Float16 hh = (_Float16)v;
                    h2h[g][(tt & 1) * 4 + r] = hh;
                    h2l[g][(tt & 1) * 4 + r] = (_Float16)((v - (float)hh) * LOSCALE);
                }
            if (tt & 1) {
                const int kc2 = t >> 1;
                const half8 a3h = *(const half8*)&p3[(size_t)kc2 * 1024 + lane*8];
                const half8 a3l = *(const half8*)&p3[(size_t)kc2 * 1024 + 512 + lane*8];
#pragma unroll
                for (int g = 0; g < 2; ++g) {
                    D1[g] = __builtin_amdgcn_mfma_f32_16x16x32_f16(a3h, h2h[g], D1[g], 0, 0, 0);
                    D2[g] = __builtin_amdgcn_mfma_f32_16x16x32_f16(a3h, h2l[g], D2[g], 0, 0, 0);
                    D2[g] = __builtin_amdgcn_mfma_f32_16x16x32_f16(a3l, h2h[g], D2[g], 0, 0, 0);
                }
            }
        }

        // ---- exchange partner-row partials via DEAD buffer sb[1] ----
        // (cur == 0 here; sb[1] holds consumed slice 7). Ternary group picks
        // keep D in registers (no runtime array index -> no scratch).
        {
            float* my = (float*)&sb[1][0] + wv * 512 + lane * 8;
            float4 w1v, w2v;
#pragma unroll
            for (int r = 0; r < 4; ++r) {
                w1v[r] = gown ? D1[0][r] : D1[1][r];   // partial for PARTNER rows
                w2v[r] = gown ? D2[0][r] : D2[1][r];
            }
            *(float4*)&my[0] = w1v;
            *(float4*)&my[4] = w2v;
        }
        __syncthreads();   // exch visible (no vmcnt outstanding here)

        float v[4];
        {
            const float* pr = (const float*)&sb[1][0] + (wv ^ 1) * 512 + lane * 8;
            const float4 p1v = *(const float4*)&pr[0];
            const float4 p2v = *(const float4*)&pr[4];
#pragma unroll
            for (int r = 0; r < 4; ++r) {
                const float o1 = gown ? D1[1][r] : D1[0][r];   // own-row partial
                const float o2 = gown ? D2[1][r] : D2[0][r];
                v[r] = (o1 + p1v[r]) + LOINV * (o2 + p2v[r]) + b3v[r];
            }
        }

        // lane (q,ln) holds sim'[own row ln][features 4q..4q+3]
        if (q == 0) {
            const float d0 = v[0] - tg[0], d1 = v[1] - tg[1], d2 = v[2] - tg[2];
            costAcc += d0 * d0 + d1 * d1 + d2 * d2;
        }
        if (q < 2) {
            const float4 w4 = {v[0], v[1], v[2], v[3]};
            *(float4*)&inpL[wv][ln][4 * q] = w4;
        } else if (q == 2) {
            inpL[wv][ln][8] = v[0];   // feature 8 only (9..11 would hit cand)
        }
        __syncthreads();   // inpL + exch consumption fenced before next step
    }

    if (q == 0) cost[(size_t)s * B + b0 + ln] = costAcc;
}

// ---------------------------------------------------------------------------
// Kernel 3: first-argmin over samples + gather best action (unchanged).
// ---------------------------------------------------------------------------
__global__ __launch_bounds__(256) void k_select(
    const float* __restrict__ cost, const float* __restrict__ cand,
    float* __restrict__ out, int B, int S)
{
    const int b = blockIdx.x * 256 + threadIdx.x;
    if (b >= B) return;
    float best = cost[b];
    int bs = 0;
    for (int s = 1; s < S; ++s) {
        const float c = cost[(size_t)s * B + b];
        if (c < best) { best = c; bs = s; }
    }
#pragma unroll
    for (int j = 0; j < NAD; ++j)
        out[b * NAD + j] = cand[((size_t)bs * B + b) * NAD + j];
}

// ---------------------------------------------------------------------------
extern "C" void kernel_launch(void* const* d_in, const int* in_sizes, int n_in,
                              void* d_out, int out_size, void* d_ws, size_t ws_size,
                              hipStream_t stream)
{
    const float* state   = (const float*)d_in[0];
    const float* proprio = (const float*)d_in[1];
    const float* target  = (const float*)d_in[2];
    const float* noise   = (const float*)d_in[3];
    const float* pw1     = (const float*)d_in[4];
    const float* pb1     = (const float*)d_in[5];
    const float* pw2     = (const float*)d_in[6];
    const float* pb2     = (const float*)d_in[7];
    const float* w1      = (const float*)d_in[8];
    const float* b1      = (const float*)d_in[9];
    const float* w2      = (const float*)d_in[10];
    const float* b2      = (const float*)d_in[11];
    const float* w3      = (const float*)d_in[12];
    const float* b3      = (const float*)d_in[13];
    const int*   horizon = (const int*)d_in[14];

    const int B = in_sizes[0] / NSD;             // 8192
    const int S = in_sizes[3] / (B * NAD);       // 8

    float* cand = (float*)d_ws;                            // S*B*7 floats
    float* cost = cand + (size_t)S * B * NAD;              // S*B floats
    _Float16* pc = (_Float16*)(cost + (size_t)S * B);      // 8*18432 fp16 (288 KB)
    _Float16* p3 = pc + 8 * 18432;                         // 8*1024 fp16 (16 KB)
    float* out  = (float*)d_out;

    k_prep<<<dim3(NPACKB + (B + 3) / 4), dim3(256), 0, stream>>>(
        w1, b1, w2, w3, pc, p3,
        state, proprio, noise, pw1, pb1, pw2, pb2, cand, B);
    k_rollout<<<dim3((S * B) / 64), dim3(256), 0, stream>>>(
        state, target, cand, pc, p3, b2, b3, horizon, cost, B);
    k_select<<<dim3((B + 255) / 256), dim3(256), 0, stream>>>(
        cost, cand, out, B, S);
}